// Round 9
// baseline (464.586 us; speedup 1.0000x reference)
//
#include <hip/hip_runtime.h>
#include <hip/hip_bf16.h>

#define B 2
#define N 20000
#define M 4096
#define S 2
#define K 25
#define J 64
#define KJ (K*J)        // 1600
#define GM 8            // m-cells per gather block
#define SROWS 4000      // rows per LDS stage (16B each -> 64 KB)
#define NSTAGE 5        // 5*4000 = 20000 exactly
#define TC 32           // MLP column tile

__device__ __forceinline__ unsigned bfbits(float x) {
    unsigned u = __float_as_uint(x);
    return (u + 0x7FFFu + ((u >> 16) & 1u)) >> 16;   // RNE bf16 bits
}

// ---------------- Kernel A: prep ----------------
__global__ __launch_bounds__(256) void prep_kernel(
    const float* __restrict__ xyz, const float* __restrict__ feature,
    const float* __restrict__ new_xyz, const float* __restrict__ conv_w,
    const float* __restrict__ w0, const float* __restrict__ w1,
    __hip_bfloat16* __restrict__ xfh, float* __restrict__ conv_wT,
    float* __restrict__ w0T, float* __restrict__ w1T,
    float* __restrict__ out_newxyz) {
    const int T1 = B * N * 8;     // 320000
    const int T2 = 208 * 64;      // 13312
    const int T3 = B * M * 3;     // 24576
    const int T4 = 128 * 128;     // 16384
    const int T5 = 128 * 256;     // 32768
    int e = blockIdx.x * blockDim.x + threadIdx.x;
    if (e < T1) {
        int r = e >> 3, t = e & 7;
        float v = (t < 2) ? xyz[r * 3 + t] : feature[r * 6 + (t - 2)];
        xfh[e] = __float2bfloat16(v);
    } else if (e < T1 + T2) {
        int e2 = e - T1;
        int i = e2 >> 6, o = e2 & 63;           // i = k*8+c
        conv_wT[e2] = (i < 200) ? conv_w[o * 200 + (i & 7) * 25 + (i >> 3)] : 0.f;
    } else if (e < T1 + T2 + T3) {
        int e3 = e - T1 - T2;
        out_newxyz[e3] = new_xyz[e3];
    } else if (e < T1 + T2 + T3 + T4) {
        int e4 = e - T1 - T2 - T3;
        int c = e4 >> 7, o = e4 & 127;          // w0T[c][o]
        w0T[e4] = w0[o * 128 + c];
    } else if (e < T1 + T2 + T3 + T4 + T5) {
        int e5 = e - T1 - T2 - T3 - T4;
        int c = e5 >> 8, o = e5 & 255;          // w1T[c][o]
        w1T[e5] = w1[o * 128 + c];
    }
}

// ---------------- Kernel B: 5-stage full-table LDS gather + conv + relu ----------------
// 2048 blocks x 256 thr, 2 blocks/CU (70.7 KB LDS). 200 active threads own one
// (m_local, k) cell = 64 packed (idx<<16|bf16w) pairs in registers. The whole
// 20000-row bf16 table streams through a 4000-row LDS buffer in 5 stages; every
// gather is an LDS read. Zero random global requests.
__global__ __launch_bounds__(256, 2) void gather_conv_kernel(
    const int* __restrict__ idx, const float* __restrict__ weight,
    const float* __restrict__ new_xyz, const uint4* __restrict__ xfh,
    const float* __restrict__ conv_wT, const float* __restrict__ conv_b,
    float* __restrict__ xmid) {
    __shared__ uint4 tab[SROWS];             // 64,000 B
    __shared__ float snf[GM][208];           // 6,656 B -> 70,656 total

    int g = blockIdx.x;
    int m8 = g & 511;                        // M/GM = 512
    int sb = g >> 9;
    int b = sb & 1;
    int s = sb >> 1;
    int m0 = m8 * GM;
    int tid = threadIdx.x;

    bool active = tid < 200;
    int mi = tid / 25;                       // 0..7
    int k  = tid - mi * 25;                  // 0..24

    // ---- load + pack this cell's 64 (idx, w) pairs into registers ----
    unsigned pk[64];
    if (active) {
        size_t base = ((((size_t)(s * B + b)) * M + m0 + mi) * K + k) * J;
        const int4*   gi4 = (const int4*)  (idx    + base);
        const float4* gw4 = (const float4*)(weight + base);
        #pragma unroll
        for (int q = 0; q < 16; ++q) {
            int4   iv = gi4[q];
            float4 wv = gw4[q];
            pk[q * 4 + 0] = ((unsigned)iv.x << 16) | bfbits(wv.x);
            pk[q * 4 + 1] = ((unsigned)iv.y << 16) | bfbits(wv.y);
            pk[q * 4 + 2] = ((unsigned)iv.z << 16) | bfbits(wv.z);
            pk[q * 4 + 3] = ((unsigned)iv.w << 16) | bfbits(wv.w);
        }
    } else {
        #pragma unroll
        for (int q = 0; q < 64; ++q) pk[q] = 0xFFFF0000u;   // idx 65535: never hits
    }

    // ---- 5-stage streamed gather: every hit is an LDS read ----
    float acc[8] = {0.f, 0.f, 0.f, 0.f, 0.f, 0.f, 0.f, 0.f};
    const uint4* src = xfh + (size_t)b * N;
    for (int st = 0; st < NSTAGE; ++st) {
        int lo = st * SROWS;
        __syncthreads();                     // previous stage fully consumed
        for (int i = tid; i < SROWS; i += 256) tab[i] = src[lo + i];
        __syncthreads();
        unsigned loB = (unsigned)lo << 16;
        #pragma unroll
        for (int p = 0; p < 64; ++p) {
            unsigned d = pk[p] - loB;        // (idx - lo) in high 16 bits
            if (d < ((unsigned)SROWS << 16)) {
                uint4 row = tab[d >> 16];
                float w = __uint_as_float(pk[p] << 16);
                acc[0] = fmaf(w, __uint_as_float(row.x << 16),         acc[0]);
                acc[1] = fmaf(w, __uint_as_float(row.x & 0xffff0000u), acc[1]);
                acc[2] = fmaf(w, __uint_as_float(row.y << 16),         acc[2]);
                acc[3] = fmaf(w, __uint_as_float(row.y & 0xffff0000u), acc[3]);
                acc[4] = fmaf(w, __uint_as_float(row.z << 16),         acc[4]);
                acc[5] = fmaf(w, __uint_as_float(row.z & 0xffff0000u), acc[5]);
                acc[6] = fmaf(w, __uint_as_float(row.w << 16),         acc[6]);
                acc[7] = fmaf(w, __uint_as_float(row.w & 0xffff0000u), acc[7]);
            }
        }
    }

    // ---- center subtract, write nf to LDS ----
    if (active) {
        float cx = new_xyz[((size_t)b * M + m0 + mi) * 3 + 0];
        float cy = new_xyz[((size_t)b * M + m0 + mi) * 3 + 1];
        acc[0] -= cx; acc[1] -= cy;
        float4* s4 = (float4*)&snf[mi][k * 8];
        s4[0] = make_float4(acc[0], acc[1], acc[2], acc[3]);
        s4[1] = make_float4(acc[4], acc[5], acc[6], acc[7]);
    }
    if (tid < 64) snf[tid >> 3][200 + (tid & 7)] = 0.f;
    __syncthreads();

    // ---- conv: 256 thr = 64 o x 4 m-slots, 2 passes; conv_wT streamed from L2 ----
    {
        int o = tid & 63, h = tid >> 6;
        #pragma unroll
        for (int pass = 0; pass < 2; ++pass) {
            int mm = pass * 4 + h;
            float a = conv_b[o];
            const float4* sm = (const float4*)snf[mm];
            #pragma unroll 5
            for (int q = 0; q < 50; ++q) {
                float4 v = sm[q];
                int i = q * 4;
                a = fmaf(v.x, conv_wT[(i + 0) * 64 + o], a);
                a = fmaf(v.y, conv_wT[(i + 1) * 64 + o], a);
                a = fmaf(v.z, conv_wT[(i + 2) * 64 + o], a);
                a = fmaf(v.w, conv_wT[(i + 3) * 64 + o], a);
            }
            a = fmaxf(a, 0.f);
            xmid[((size_t)b * M + m0 + mm) * 128 + s * 64 + o] = a;   // [col][c]
        }
    }
}

// ---------------- Kernel C0: MLP0 + relu (in-place xmid [col][128]) ----------------
__global__ __launch_bounds__(256) void mlp0_kernel(
    float* __restrict__ xmid,
    const float* __restrict__ w0T, const float* __restrict__ b0) {
    __shared__ float ws[128 * 128];   // 64 KB, [c][o]
    __shared__ float xs[128 * 32];    // 16 KB, [c][col]

    int tid = threadIdx.x;
    int col0 = blockIdx.x * TC;

    {
        const float4* w4 = (const float4*)w0T;
        float4* ws4 = (float4*)ws;
        #pragma unroll
        for (int i = 0; i < 16; ++i) ws4[tid + 256 * i] = w4[tid + 256 * i];
    }
    {
        const float4* xm4 = (const float4*)(xmid + (size_t)col0 * 128);
        #pragma unroll
        for (int r = tid; r < 1024; r += 256) {
            int lc = r >> 5, c4 = r & 31;
            float4 v = xm4[lc * 32 + c4];
            int c = c4 * 4;
            xs[(c + 0) * 32 + lc] = v.x;
            xs[(c + 1) * 32 + lc] = v.y;
            xs[(c + 2) * 32 + lc] = v.z;
            xs[(c + 3) * 32 + lc] = v.w;
        }
    }
    __syncthreads();

    int og = tid >> 3, cg = tid & 7;
    int o0 = og * 4, lc0 = cg * 4;
    float acc[4][4];
    #pragma unroll
    for (int i = 0; i < 4; ++i) {
        float bv = b0[o0 + i];
        #pragma unroll
        for (int u = 0; u < 4; ++u) acc[i][u] = bv;
    }
    for (int c = 0; c < 128; ++c) {
        float4 xv = *(const float4*)&xs[c * 32 + lc0];
        float4 wv = *(const float4*)&ws[c * 128 + o0];
        acc[0][0] = fmaf(wv.x, xv.x, acc[0][0]);
        acc[0][1] = fmaf(wv.x, xv.y, acc[0][1]);
        acc[0][2] = fmaf(wv.x, xv.z, acc[0][2]);
        acc[0][3] = fmaf(wv.x, xv.w, acc[0][3]);
        acc[1][0] = fmaf(wv.y, xv.x, acc[1][0]);
        acc[1][1] = fmaf(wv.y, xv.y, acc[1][1]);
        acc[1][2] = fmaf(wv.y, xv.z, acc[1][2]);
        acc[1][3] = fmaf(wv.y, xv.w, acc[1][3]);
        acc[2][0] = fmaf(wv.z, xv.x, acc[2][0]);
        acc[2][1] = fmaf(wv.z, xv.y, acc[2][1]);
        acc[2][2] = fmaf(wv.z, xv.z, acc[2][2]);
        acc[2][3] = fmaf(wv.z, xv.w, acc[2][3]);
        acc[3][0] = fmaf(wv.w, xv.x, acc[3][0]);
        acc[3][1] = fmaf(wv.w, xv.y, acc[3][1]);
        acc[3][2] = fmaf(wv.w, xv.z, acc[3][2]);
        acc[3][3] = fmaf(wv.w, xv.w, acc[3][3]);
    }
    #pragma unroll
    for (int u = 0; u < 4; ++u) {
        float4 v = make_float4(fmaxf(acc[0][u], 0.f), fmaxf(acc[1][u], 0.f),
                               fmaxf(acc[2][u], 0.f), fmaxf(acc[3][u], 0.f));
        *(float4*)&xmid[(size_t)(col0 + lc0 + u) * 128 + o0] = v;
    }
}

// ---------------- Kernel C1: MLP1 + relu + store (o-split) ----------------
__global__ __launch_bounds__(256) void mlp1_kernel(
    const float* __restrict__ xmid,
    const float* __restrict__ w1T, const float* __restrict__ b1,
    float* __restrict__ out_rf) {
    __shared__ float ws[128 * 128];   // 64 KB, [c][o-half]
    __shared__ float xs[128 * 32];    // 16 KB

    int tid = threadIdx.x;
    int bx = blockIdx.x;
    int col0 = (bx >> 1) * TC;
    int oH = (bx & 1) * 128;

    {
        for (int i = tid; i < 4096; i += 256) {
            int c = i >> 5, q = i & 31;
            *(float4*)&ws[c * 128 + q * 4] = *(const float4*)&w1T[c * 256 + oH + q * 4];
        }
    }
    {
        const float4* xm4 = (const float4*)(xmid + (size_t)col0 * 128);
        #pragma unroll
        for (int r = tid; r < 1024; r += 256) {
            int lc = r >> 5, c4 = r & 31;
            float4 v = xm4[lc * 32 + c4];
            int c = c4 * 4;
            xs[(c + 0) * 32 + lc] = v.x;
            xs[(c + 1) * 32 + lc] = v.y;
            xs[(c + 2) * 32 + lc] = v.z;
            xs[(c + 3) * 32 + lc] = v.w;
        }
    }
    __syncthreads();

    int og = tid >> 3, cg = tid & 7;
    int o0 = og * 4, lc0 = cg * 4;
    float acc[4][4];
    #pragma unroll
    for (int i = 0; i < 4; ++i) {
        float bv = b1[oH + o0 + i];
        #pragma unroll
        for (int u = 0; u < 4; ++u) acc[i][u] = bv;
    }
    for (int c = 0; c < 128; ++c) {
        float4 xv = *(const float4*)&xs[c * 32 + lc0];
        float4 wv = *(const float4*)&ws[c * 128 + o0];
        acc[0][0] = fmaf(wv.x, xv.x, acc[0][0]);
        acc[0][1] = fmaf(wv.x, xv.y, acc[0][1]);
        acc[0][2] = fmaf(wv.x, xv.z, acc[0][2]);
        acc[0][3] = fmaf(wv.x, xv.w, acc[0][3]);
        acc[1][0] = fmaf(wv.y, xv.x, acc[1][0]);
        acc[1][1] = fmaf(wv.y, xv.y, acc[1][1]);
        acc[1][2] = fmaf(wv.y, xv.z, acc[1][2]);
        acc[1][3] = fmaf(wv.y, xv.w, acc[1][3]);
        acc[2][0] = fmaf(wv.z, xv.x, acc[2][0]);
        acc[2][1] = fmaf(wv.z, xv.y, acc[2][1]);
        acc[2][2] = fmaf(wv.z, xv.z, acc[2][2]);
        acc[2][3] = fmaf(wv.z, xv.w, acc[2][3]);
        acc[3][0] = fmaf(wv.w, xv.x, acc[3][0]);
        acc[3][1] = fmaf(wv.w, xv.y, acc[3][1]);
        acc[3][2] = fmaf(wv.w, xv.z, acc[3][2]);
        acc[3][3] = fmaf(wv.w, xv.w, acc[3][3]);
    }
    #pragma unroll
    for (int u = 0; u < 4; ++u) {
        float4 v = make_float4(fmaxf(acc[0][u], 0.f), fmaxf(acc[1][u], 0.f),
                               fmaxf(acc[2][u], 0.f), fmaxf(acc[3][u], 0.f));
        *(float4*)&out_rf[(size_t)(col0 + lc0 + u) * 256 + oH + o0] = v;
    }
}

extern "C" void kernel_launch(void* const* d_in, const int* in_sizes, int n_in,
                              void* d_out, int out_size, void* d_ws, size_t ws_size,
                              hipStream_t stream) {
    const float* xyz     = (const float*)d_in[0];
    const float* feature = (const float*)d_in[1];
    const float* new_xyz = (const float*)d_in[2];
    const int*   idx     = (const int*)  d_in[3];
    const float* weight  = (const float*)d_in[4];
    const float* conv_w  = (const float*)d_in[5];
    const float* conv_b  = (const float*)d_in[6];
    const float* mlp_w0  = (const float*)d_in[7];
    const float* mlp_b0  = (const float*)d_in[8];
    const float* mlp_w1  = (const float*)d_in[9];
    const float* mlp_b1  = (const float*)d_in[10];

    float* out    = (float*)d_out;
    float* out_rf = out + (size_t)B * M * 3;

    float* wsf = (float*)d_ws;
    __hip_bfloat16* xfh = (__hip_bfloat16*)wsf;  // 320000 bf16
    float* conv_wT = wsf + 160000;               // 13312
    float* xmid    = conv_wT + 13312;            // B*M*128, [col][c]
    float* w0T     = xmid + 1048576;             // 16384
    float* w1T     = w0T + 16384;                // 32768

    {
        int total = 320000 + 13312 + 24576 + 16384 + 32768;
        int blocks = (total + 255) / 256;
        prep_kernel<<<blocks, 256, 0, stream>>>(xyz, feature, new_xyz, conv_w,
                                                mlp_w0, mlp_w1,
                                                xfh, conv_wT, w0T, w1T, out);
    }
    {
        int blocks = S * B * (M / GM);          // 2048
        gather_conv_kernel<<<blocks, 256, 0, stream>>>(idx, weight, new_xyz,
                                                       (const uint4*)xfh,
                                                       conv_wT, conv_b, xmid);
    }
    {
        mlp0_kernel<<<(B * M) / TC, 256, 0, stream>>>(xmid, w0T, mlp_b0);
    }
    {
        mlp1_kernel<<<2 * (B * M) / TC, 256, 0, stream>>>(xmid, w1T, mlp_b1, out_rf);
    }
}

// Round 10
// 363.931 us; speedup vs baseline: 1.2766x; 1.2766x over previous
//
#include <hip/hip_runtime.h>
#include <hip/hip_bf16.h>

#define B 2
#define N 20000
#define M 4096
#define S 2
#define K 25
#define J 64
#define KJ (K*J)        // 1600
#define TC 32           // MLP column tile

// ---------------- Kernel A: prep ----------------
__global__ __launch_bounds__(256) void prep_kernel(
    const float* __restrict__ xyz, const float* __restrict__ feature,
    const float* __restrict__ new_xyz, const float* __restrict__ conv_w,
    const float* __restrict__ w0, const float* __restrict__ w1,
    __hip_bfloat16* __restrict__ xfh, float* __restrict__ conv_wT,
    float* __restrict__ w0T, float* __restrict__ w1T,
    float* __restrict__ out_newxyz) {
    const int T1 = B * N * 8;     // 320000
    const int T2 = 208 * 64;      // 13312
    const int T3 = B * M * 3;     // 24576
    const int T4 = 128 * 128;     // 16384
    const int T5 = 128 * 256;     // 32768
    int e = blockIdx.x * blockDim.x + threadIdx.x;
    if (e < T1) {
        int r = e >> 3, t = e & 7;
        float v = (t < 2) ? xyz[r * 3 + t] : feature[r * 6 + (t - 2)];
        xfh[e] = __float2bfloat16(v);
    } else if (e < T1 + T2) {
        int e2 = e - T1;
        int i = e2 >> 6, o = e2 & 63;           // i = k*8+c
        conv_wT[e2] = (i < 200) ? conv_w[o * 200 + (i & 7) * 25 + (i >> 3)] : 0.f;
    } else if (e < T1 + T2 + T3) {
        int e3 = e - T1 - T2;
        out_newxyz[e3] = new_xyz[e3];
    } else if (e < T1 + T2 + T3 + T4) {
        int e4 = e - T1 - T2 - T3;
        int c = e4 >> 7, o = e4 & 127;          // w0T[c][o]
        w0T[e4] = w0[o * 128 + c];
    } else if (e < T1 + T2 + T3 + T4 + T5) {
        int e5 = e - T1 - T2 - T3 - T4;
        int c = e5 >> 8, o = e5 & 255;          // w1T[c][o]
        w1T[e5] = w1[o * 128 + c];
    }
}

// ---------------- Kernel B: gather (bf16 rows, sc0 L1-bypass) + conv + relu ----------------
// At the L2 random-request roofline: 26.2M 16B requests / (8 req/cyc/XCD * 8 XCD
// * 2.4 GHz) = 170.7 us model vs ~174 us measured (98%).
__global__ __launch_bounds__(256) void gather_conv_kernel(
    const int* __restrict__ idx, const float* __restrict__ weight,
    const float* __restrict__ new_xyz, const uint4* __restrict__ xfh,
    const float* __restrict__ conv_wT, const float* __restrict__ conv_b,
    float* __restrict__ xmid) {
    __shared__ float snf[208];
    __shared__ float spart[4][64];

    int g = blockIdx.x;               // g = (s*B + b)*M + m
    int m = g & (M - 1);
    int sb = g >> 12;
    int b = sb & (B - 1);
    int s = sb >> 1;
    int tid = threadIdx.x;

    if (tid >= 200 && tid < 208) snf[tid] = 0.f;

    if (tid < 200) {
        const int4*   gi4 = (const int4*)  (idx    + (size_t)g * KJ);
        const float4* gw4 = (const float4*)(weight + (size_t)g * KJ);
        int4   ia = gi4[tid * 2], ib = gi4[tid * 2 + 1];
        float4 wa = gw4[tid * 2], wb = gw4[tid * 2 + 1];

        const uint4* xfb = xfh + (size_t)b * N;   // one 16B row per point
        float wsv[8]  = {wa.x, wa.y, wa.z, wa.w, wb.x, wb.y, wb.z, wb.w};

        uint4 r0, r1, r2, r3, r4, r5, r6, r7;
        {
            const uint4* a0 = xfb + ia.x;
            const uint4* a1 = xfb + ia.y;
            const uint4* a2 = xfb + ia.z;
            const uint4* a3 = xfb + ia.w;
            const uint4* a4 = xfb + ib.x;
            const uint4* a5 = xfb + ib.y;
            const uint4* a6 = xfb + ib.z;
            const uint4* a7 = xfb + ib.w;
            asm volatile(
                "global_load_dwordx4 %0, %8, off sc0\n\t"
                "global_load_dwordx4 %1, %9, off sc0\n\t"
                "global_load_dwordx4 %2, %10, off sc0\n\t"
                "global_load_dwordx4 %3, %11, off sc0\n\t"
                "global_load_dwordx4 %4, %12, off sc0\n\t"
                "global_load_dwordx4 %5, %13, off sc0\n\t"
                "global_load_dwordx4 %6, %14, off sc0\n\t"
                "global_load_dwordx4 %7, %15, off sc0\n\t"
                "s_waitcnt vmcnt(0)"
                : "=&v"(r0), "=&v"(r1), "=&v"(r2), "=&v"(r3),
                  "=&v"(r4), "=&v"(r5), "=&v"(r6), "=&v"(r7)
                : "v"(a0), "v"(a1), "v"(a2), "v"(a3),
                  "v"(a4), "v"(a5), "v"(a6), "v"(a7));
        }

        float acc[8] = {0.f,0.f,0.f,0.f,0.f,0.f,0.f,0.f};
        uint4 rr[8] = {r0, r1, r2, r3, r4, r5, r6, r7};
        #pragma unroll
        for (int j = 0; j < 8; ++j) {
            uint4 r = rr[j];
            float w = wsv[j];
            acc[0] = fmaf(w, __uint_as_float(r.x << 16),          acc[0]);
            acc[1] = fmaf(w, __uint_as_float(r.x & 0xffff0000u),  acc[1]);
            acc[2] = fmaf(w, __uint_as_float(r.y << 16),          acc[2]);
            acc[3] = fmaf(w, __uint_as_float(r.y & 0xffff0000u),  acc[3]);
            acc[4] = fmaf(w, __uint_as_float(r.z << 16),          acc[4]);
            acc[5] = fmaf(w, __uint_as_float(r.z & 0xffff0000u),  acc[5]);
            acc[6] = fmaf(w, __uint_as_float(r.w << 16),          acc[6]);
            acc[7] = fmaf(w, __uint_as_float(r.w & 0xffff0000u),  acc[7]);
        }
        #pragma unroll
        for (int d = 1; d < 8; d <<= 1) {
            #pragma unroll
            for (int c = 0; c < 8; ++c) acc[c] += __shfl_xor(acc[c], d, 64);
        }
        if ((tid & 7) == 0) {
            int kk = tid >> 3;
            float cx = new_xyz[(b * M + m) * 3 + 0];
            float cy = new_xyz[(b * M + m) * 3 + 1];
            acc[0] -= cx; acc[1] -= cy;
            float4* s4 = (float4*)&snf[kk * 8];
            s4[0] = make_float4(acc[0], acc[1], acc[2], acc[3]);
            s4[1] = make_float4(acc[4], acc[5], acc[6], acc[7]);
        }
    }
    __syncthreads();

    // conv: 256 threads = 64 o x 4 parts
    int o = tid & 63, p = tid >> 6;
    const float4* snf4 = (const float4*)snf;
    float acc2 = 0.f;
    #pragma unroll
    for (int q = 0; q < 13; ++q) {
        float4 v = snf4[p * 13 + q];
        int i = (p * 13 + q) * 4;
        acc2 = fmaf(v.x, conv_wT[(i + 0) * 64 + o], acc2);
        acc2 = fmaf(v.y, conv_wT[(i + 1) * 64 + o], acc2);
        acc2 = fmaf(v.z, conv_wT[(i + 2) * 64 + o], acc2);
        acc2 = fmaf(v.w, conv_wT[(i + 3) * 64 + o], acc2);
    }
    spart[p][o] = acc2;
    __syncthreads();

    if (tid < 64) {
        float v = spart[0][tid] + spart[1][tid] + spart[2][tid] + spart[3][tid] + conv_b[tid];
        v = fmaxf(v, 0.f);
        xmid[((size_t)(b * M + m)) * 128 + s * 64 + tid] = v;   // [col][c]
    }
}

// ---------------- Kernel C0: MLP0 + relu (in-place xmid [col][128]) ----------------
__global__ __launch_bounds__(256) void mlp0_kernel(
    float* __restrict__ xmid,
    const float* __restrict__ w0T, const float* __restrict__ b0) {
    __shared__ float ws[128 * 128];   // 64 KB, [c][o]
    __shared__ float xs[128 * 32];    // 16 KB, [c][col]

    int tid = threadIdx.x;
    int col0 = blockIdx.x * TC;

    {
        const float4* w4 = (const float4*)w0T;
        float4* ws4 = (float4*)ws;
        #pragma unroll
        for (int i = 0; i < 16; ++i) ws4[tid + 256 * i] = w4[tid + 256 * i];
    }
    {
        const float4* xm4 = (const float4*)(xmid + (size_t)col0 * 128);
        #pragma unroll
        for (int r = tid; r < 1024; r += 256) {
            int lc = r >> 5, c4 = r & 31;
            float4 v = xm4[lc * 32 + c4];
            int c = c4 * 4;
            xs[(c + 0) * 32 + lc] = v.x;
            xs[(c + 1) * 32 + lc] = v.y;
            xs[(c + 2) * 32 + lc] = v.z;
            xs[(c + 3) * 32 + lc] = v.w;
        }
    }
    __syncthreads();

    int og = tid >> 3, cg = tid & 7;
    int o0 = og * 4, lc0 = cg * 4;
    float acc[4][4];
    #pragma unroll
    for (int i = 0; i < 4; ++i) {
        float bv = b0[o0 + i];
        #pragma unroll
        for (int u = 0; u < 4; ++u) acc[i][u] = bv;
    }
    for (int c = 0; c < 128; ++c) {
        float4 xv = *(const float4*)&xs[c * 32 + lc0];
        float4 wv = *(const float4*)&ws[c * 128 + o0];
        acc[0][0] = fmaf(wv.x, xv.x, acc[0][0]);
        acc[0][1] = fmaf(wv.x, xv.y, acc[0][1]);
        acc[0][2] = fmaf(wv.x, xv.z, acc[0][2]);
        acc[0][3] = fmaf(wv.x, xv.w, acc[0][3]);
        acc[1][0] = fmaf(wv.y, xv.x, acc[1][0]);
        acc[1][1] = fmaf(wv.y, xv.y, acc[1][1]);
        acc[1][2] = fmaf(wv.y, xv.z, acc[1][2]);
        acc[1][3] = fmaf(wv.y, xv.w, acc[1][3]);
        acc[2][0] = fmaf(wv.z, xv.x, acc[2][0]);
        acc[2][1] = fmaf(wv.z, xv.y, acc[2][1]);
        acc[2][2] = fmaf(wv.z, xv.z, acc[2][2]);
        acc[2][3] = fmaf(wv.z, xv.w, acc[2][3]);
        acc[3][0] = fmaf(wv.w, xv.x, acc[3][0]);
        acc[3][1] = fmaf(wv.w, xv.y, acc[3][1]);
        acc[3][2] = fmaf(wv.w, xv.z, acc[3][2]);
        acc[3][3] = fmaf(wv.w, xv.w, acc[3][3]);
    }
    #pragma unroll
    for (int u = 0; u < 4; ++u) {
        float4 v = make_float4(fmaxf(acc[0][u], 0.f), fmaxf(acc[1][u], 0.f),
                               fmaxf(acc[2][u], 0.f), fmaxf(acc[3][u], 0.f));
        *(float4*)&xmid[(size_t)(col0 + lc0 + u) * 128 + o0] = v;
    }
}

// ---------------- Kernel C1: MLP1 + relu + store (o-split) ----------------
__global__ __launch_bounds__(256) void mlp1_kernel(
    const float* __restrict__ xmid,
    const float* __restrict__ w1T, const float* __restrict__ b1,
    float* __restrict__ out_rf) {
    __shared__ float ws[128 * 128];   // 64 KB, [c][o-half]
    __shared__ float xs[128 * 32];    // 16 KB

    int tid = threadIdx.x;
    int bx = blockIdx.x;
    int col0 = (bx >> 1) * TC;
    int oH = (bx & 1) * 128;

    {
        for (int i = tid; i < 4096; i += 256) {
            int c = i >> 5, q = i & 31;
            *(float4*)&ws[c * 128 + q * 4] = *(const float4*)&w1T[c * 256 + oH + q * 4];
        }
    }
    {
        const float4* xm4 = (const float4*)(xmid + (size_t)col0 * 128);
        #pragma unroll
        for (int r = tid; r < 1024; r += 256) {
            int lc = r >> 5, c4 = r & 31;
            float4 v = xm4[lc * 32 + c4];
            int c = c4 * 4;
            xs[(c + 0) * 32 + lc] = v.x;
            xs[(c + 1) * 32 + lc] = v.y;
            xs[(c + 2) * 32 + lc] = v.z;
            xs[(c + 3) * 32 + lc] = v.w;
        }
    }
    __syncthreads();

    int og = tid >> 3, cg = tid & 7;
    int o0 = og * 4, lc0 = cg * 4;
    float acc[4][4];
    #pragma unroll
    for (int i = 0; i < 4; ++i) {
        float bv = b1[oH + o0 + i];
        #pragma unroll
        for (int u = 0; u < 4; ++u) acc[i][u] = bv;
    }
    for (int c = 0; c < 128; ++c) {
        float4 xv = *(const float4*)&xs[c * 32 + lc0];
        float4 wv = *(const float4*)&ws[c * 128 + o0];
        acc[0][0] = fmaf(wv.x, xv.x, acc[0][0]);
        acc[0][1] = fmaf(wv.x, xv.y, acc[0][1]);
        acc[0][2] = fmaf(wv.x, xv.z, acc[0][2]);
        acc[0][3] = fmaf(wv.x, xv.w, acc[0][3]);
        acc[1][0] = fmaf(wv.y, xv.x, acc[1][0]);
        acc[1][1] = fmaf(wv.y, xv.y, acc[1][1]);
        acc[1][2] = fmaf(wv.y, xv.z, acc[1][2]);
        acc[1][3] = fmaf(wv.y, xv.w, acc[1][3]);
        acc[2][0] = fmaf(wv.z, xv.x, acc[2][0]);
        acc[2][1] = fmaf(wv.z, xv.y, acc[2][1]);
        acc[2][2] = fmaf(wv.z, xv.z, acc[2][2]);
        acc[2][3] = fmaf(wv.z, xv.w, acc[2][3]);
        acc[3][0] = fmaf(wv.w, xv.x, acc[3][0]);
        acc[3][1] = fmaf(wv.w, xv.y, acc[3][1]);
        acc[3][2] = fmaf(wv.w, xv.z, acc[3][2]);
        acc[3][3] = fmaf(wv.w, xv.w, acc[3][3]);
    }
    #pragma unroll
    for (int u = 0; u < 4; ++u) {
        float4 v = make_float4(fmaxf(acc[0][u], 0.f), fmaxf(acc[1][u], 0.f),
                               fmaxf(acc[2][u], 0.f), fmaxf(acc[3][u], 0.f));
        *(float4*)&out_rf[(size_t)(col0 + lc0 + u) * 256 + oH + o0] = v;
    }
}

extern "C" void kernel_launch(void* const* d_in, const int* in_sizes, int n_in,
                              void* d_out, int out_size, void* d_ws, size_t ws_size,
                              hipStream_t stream) {
    const float* xyz     = (const float*)d_in[0];
    const float* feature = (const float*)d_in[1];
    const float* new_xyz = (const float*)d_in[2];
    const int*   idx     = (const int*)  d_in[3];
    const float* weight  = (const float*)d_in[4];
    const float* conv_w  = (const float*)d_in[5];
    const float* conv_b  = (const float*)d_in[6];
    const float* mlp_w0  = (const float*)d_in[7];
    const float* mlp_b0  = (const float*)d_in[8];
    const float* mlp_w1  = (const float*)d_in[9];
    const float* mlp_b1  = (const float*)d_in[10];

    float* out    = (float*)d_out;
    float* out_rf = out + (size_t)B * M * 3;

    float* wsf = (float*)d_ws;
    __hip_bfloat16* xfh = (__hip_bfloat16*)wsf;  // 320000 bf16
    float* conv_wT = wsf + 160000;               // 13312
    float* xmid    = conv_wT + 13312;            // B*M*128, [col][c]
    float* w0T     = xmid + 1048576;             // 16384
    float* w1T     = w0T + 16384;                // 32768

    {
        int total = 320000 + 13312 + 24576 + 16384 + 32768;
        int blocks = (total + 255) / 256;
        prep_kernel<<<blocks, 256, 0, stream>>>(xyz, feature, new_xyz, conv_w,
                                                mlp_w0, mlp_w1,
                                                xfh, conv_wT, w0T, w1T, out);
    }
    {
        int blocks = S * B * M;                 // 16384
        gather_conv_kernel<<<blocks, 256, 0, stream>>>(idx, weight, new_xyz,
                                                       (const uint4*)xfh,
                                                       conv_wT, conv_b, xmid);
    }
    {
        mlp0_kernel<<<(B * M) / TC, 256, 0, stream>>>(xmid, w0T, mlp_b0);
    }
    {
        mlp1_kernel<<<2 * (B * M) / TC, 256, 0, stream>>>(xmid, w1T, mlp_b1, out_rf);
    }
}